// Round 6
// baseline (172.889 us; speedup 1.0000x reference)
//
#include <hip/hip_runtime.h>
#include <hip/hip_bf16.h>

typedef short bf16x8 __attribute__((ext_vector_type(8)));
typedef float f32x4 __attribute__((ext_vector_type(4)));
typedef float f32x16 __attribute__((ext_vector_type(16)));
typedef unsigned short u16;
typedef unsigned int u32;

__device__ __forceinline__ u16 f2b(float f) {
  __hip_bfloat16 h = __float2bfloat16(f);
  return *reinterpret_cast<u16*>(&h);
}

#define MFMA16(a, b, c) __builtin_amdgcn_mfma_f32_16x16x32_bf16((a), (b), (c), 0, 0, 0)
#define MFMA32(a, b, c) __builtin_amdgcn_mfma_f32_32x32x16_bf16((a), (b), (c), 0, 0, 0)

// B=2 S=2048 D=1024 H=16 DC=64 HC=16 HD=64

// ---------- fp32 -> bf16 elementwise (n multiple of 1024) ----------
__global__ void k_cvt(const float* __restrict__ in, u16* __restrict__ out, int n) {
  int i = (blockIdx.x * 256 + threadIdx.x) * 4;
  if (i >= n) return;
  float4 v = *reinterpret_cast<const float4*>(in + i);
  ushort4 o;
  o.x = f2b(v.x); o.y = f2b(v.y); o.z = f2b(v.z); o.w = f2b(v.w);
  *reinterpret_cast<ushort4*>(out + i) = o;
}

// ---------- transpose + convert 1024x1024 fp32 weight -> bf16 W^T ----------
__global__ void k_wT(const float* __restrict__ W, u16* __restrict__ WT) {
  __shared__ float t[64][65];
  int tid = threadIdx.x;
  int r0 = (blockIdx.x & 15) << 6;   // k-tile
  int c0 = (blockIdx.x >> 4) << 6;   // n-tile
#pragma unroll
  for (int rep = 0; rep < 4; ++rep) {
    int e = tid + rep * 256;
    int r = e >> 4, c4 = (e & 15) << 2;
    float4 v = *reinterpret_cast<const float4*>(W + (size_t)(r0 + r) * 1024 + c0 + c4);
    t[r][c4] = v.x; t[r][c4 + 1] = v.y; t[r][c4 + 2] = v.z; t[r][c4 + 3] = v.w;
  }
  __syncthreads();
#pragma unroll
  for (int rep = 0; rep < 4; ++rep) {
    int e = tid + rep * 256;
    int c = e >> 4, r4 = (e & 15) << 2;
    ushort4 o;
    o.x = f2b(t[r4][c]); o.y = f2b(t[r4 + 1][c]);
    o.z = f2b(t[r4 + 2][c]); o.w = f2b(t[r4 + 3][c]);
    *reinterpret_cast<ushort4*>(WT + (size_t)(c0 + c) * 1024 + r0 + r4) = o;
  }
}

// ---------- z = coords @ Wc + bc ; Z bf16 [BH][S][16], zsq fp32 [BH][S] ----------
__global__ void k_z(const float* __restrict__ C, const float* __restrict__ Wc,
                    const float* __restrict__ bc, u16* __restrict__ Z,
                    float* __restrict__ zsq) {
  int gid = blockIdx.x * 256 + threadIdx.x;  // 65536 = (B*S)*H
  int bs = gid >> 4, h = gid & 15;
  const float* crow = C + (size_t)bs * 64;
  float acc[16];
#pragma unroll
  for (int c = 0; c < 16; ++c) acc[c] = bc[h * 16 + c];
  for (int k = 0; k < 64; ++k) {
    float cv = crow[k];
    const float* wr = Wc + (size_t)k * 256 + h * 16;
#pragma unroll
    for (int c = 0; c < 16; ++c) acc[c] = fmaf(cv, wr[c], acc[c]);
  }
  float sq = 0.f;
  u16 tmp[16];
#pragma unroll
  for (int c = 0; c < 16; ++c) { sq += acc[c] * acc[c]; tmp[c] = f2b(acc[c]); }
  int b = bs >> 11, s = bs & 2047;
  int bh = (b << 4) + h;
  u16* zr = Z + (((size_t)bh << 11) + s) * 16;
  *reinterpret_cast<uint4*>(zr) = *reinterpret_cast<uint4*>(tmp);
  *reinterpret_cast<uint4*>(zr + 8) = *reinterpret_cast<uint4*>(tmp + 8);
  zsq[((size_t)bh << 11) + s] = sq;
}

// ---------- GEMM C = A(bf16 MxK) * B(bf16, given as B^T NxK) + bias ----------
template <int OUTM>
__global__ __launch_bounds__(256) void k_gemm(const u16* __restrict__ A,
                                              const u16* __restrict__ BT,
                                              const float* __restrict__ bias,
                                              void* __restrict__ Cout,
                                              int M, int N, int K) {
  __shared__ u16 As[128][40];
  __shared__ u16 Bs[64][40];
  int nbn = N >> 6;
  int bm = blockIdx.x / nbn, bn = blockIdx.x % nbn;
  int tid = threadIdx.x, lane = tid & 63, w = tid >> 6;
  int wm = w >> 1, wn = w & 1;
  int l15 = lane & 15, lg = lane >> 4;
  f32x4 zero = {0.f, 0.f, 0.f, 0.f};
  f32x4 acc[4][2];
#pragma unroll
  for (int mi = 0; mi < 4; ++mi)
#pragma unroll
    for (int ni = 0; ni < 2; ++ni) acc[mi][ni] = zero;

  int ar = tid >> 2, aq = (tid & 3) << 3;
  const u16* Abase = A + (size_t)(bm * 128) * K;
  const u16* Bbase = BT + (size_t)(bn * 64) * K;

  for (int kk = 0; kk < K; kk += 32) {
    __syncthreads();
    *reinterpret_cast<uint4*>(&As[ar][aq]) =
        *reinterpret_cast<const uint4*>(Abase + (size_t)ar * K + kk + aq);
    *reinterpret_cast<uint4*>(&As[ar + 64][aq]) =
        *reinterpret_cast<const uint4*>(Abase + (size_t)(ar + 64) * K + kk + aq);
    *reinterpret_cast<uint4*>(&Bs[ar][aq]) =
        *reinterpret_cast<const uint4*>(Bbase + (size_t)ar * K + kk + aq);
    __syncthreads();
    bf16x8 af[4], bfr[2];
#pragma unroll
    for (int mi = 0; mi < 4; ++mi)
      af[mi] = *reinterpret_cast<const bf16x8*>(&As[wm * 64 + mi * 16 + l15][lg * 8]);
#pragma unroll
    for (int ni = 0; ni < 2; ++ni)
      bfr[ni] = *reinterpret_cast<const bf16x8*>(&Bs[wn * 32 + ni * 16 + l15][lg * 8]);
#pragma unroll
    for (int mi = 0; mi < 4; ++mi)
#pragma unroll
      for (int ni = 0; ni < 2; ++ni)
        acc[mi][ni] = MFMA16(af[mi], bfr[ni], acc[mi][ni]);
  }
#pragma unroll
  for (int mi = 0; mi < 4; ++mi) {
#pragma unroll
    for (int ni = 0; ni < 2; ++ni) {
      int col = bn * 64 + wn * 32 + ni * 16 + l15;
      float bb = bias[col];
#pragma unroll
      for (int j = 0; j < 4; ++j) {
        int row = bm * 128 + wm * 64 + mi * 16 + lg * 4 + j;
        float v = acc[mi][ni][j] + bb;
        if (OUTM == 0) {
          reinterpret_cast<float*>(Cout)[(size_t)row * N + col] = v;
        } else {
          int b = row >> 11, s = row & 2047, h = col >> 6, hd = col & 63;
          reinterpret_cast<u16*>(Cout)[((((size_t)(b * 16 + h) << 11) | s) << 6) + hd] = f2b(v);
        }
      }
    }
  }
}

// ---------- V [BH][S][64] -> VT [BH][64][S]  (bf16) ----------
__global__ void k_vT(const u16* __restrict__ V, u16* __restrict__ VT) {
  __shared__ u16 t[64][72];
  int tid = threadIdx.x;
  int bh = blockIdx.x >> 5;
  int s0 = (blockIdx.x & 31) << 6;
#pragma unroll
  for (int rep = 0; rep < 2; ++rep) {
    int e = tid + rep * 256;
    int sl = e >> 3, seg = (e & 7) << 3;
    *reinterpret_cast<uint4*>(&t[sl][seg]) =
        *reinterpret_cast<const uint4*>(V + ((size_t)(bh * 2048 + s0 + sl) << 6) + seg);
  }
  __syncthreads();
#pragma unroll
  for (int rep = 0; rep < 2; ++rep) {
    int e = tid + rep * 256;
    int hd = e >> 3, ss = (e & 7) << 3;
    u16 tmp[8];
#pragma unroll
    for (int i = 0; i < 8; ++i) tmp[i] = t[ss + i][hd];
    *reinterpret_cast<uint4*>(VT + ((size_t)(bh * 64 + hd) << 11) + s0 + ss) =
        *reinterpret_cast<uint4*>(tmp);
  }
}

// ---------- flash attention over gravity scores ----------
// sc = 2*dot - |zq|^2 - |zt|^2 entirely in MFMA (aug fragments).
// p = exp2(min(g2*sc,0)). P never touches LDS: after v_cvt_pk_bf16_f32, four
// v_permlane32_swap_b32 redistribute the packed P pairs between lane and
// lane^32, directly forming the PV A-fragments (k = hi*8+i layout).
// Main loop has ZERO LDS operations and zero barriers.
__global__ __launch_bounds__(256, 4) void k_attn(const u16* __restrict__ Z,
                                                 const float* __restrict__ zsq,
                                                 const u16* __restrict__ VT,
                                                 const float* __restrict__ gamma,
                                                 u16* __restrict__ O) {
  // smem: [0,16384) end-phase oacc spill; [17408,17920) psq[4][32].
  __shared__ __align__(16) char smem[17920];
  float* psqf = reinterpret_cast<float*>(smem + 17408);

  int tid = threadIdx.x, lane = tid & 63, w = tid >> 6;
  int l31 = lane & 31, hi = lane >> 5;
  int hi4 = hi << 2, hi8 = hi << 3;
  int th = w >> 1, qh = w & 1, th32 = th << 5;
  int bh = blockIdx.x >> 5, qt = blockIdx.x & 31;
  int q0 = qt << 6;
  int h = bh & 15, bb = bh >> 4;
  float gm = gamma[h];
  float g = (gm > 15.f) ? gm : log1pf(__expf(gm));  // softplus
  float g2 = g * 1.4426950408889634f;               // fold log2(e) -> exp2

  const u16* Zb = Z + ((size_t)bh << 11) * 16;
  const float* zsb = zsq + ((size_t)bh << 11);
  const u16* VTb = VT + ((size_t)bh << 6) * 2048;

  int q = (qh << 5) + l31;              // this lane's q (local to 64-tile)

  // Q B-fragment, pre-doubled: bf16 *2 == exponent+1 (exact for normals)
  uint4 zqu = *reinterpret_cast<const uint4*>(Zb + (size_t)(q0 + q) * 16 + hi8);
  zqu.x += 0x00800080u; zqu.y += 0x00800080u;
  zqu.z += 0x00800080u; zqu.w += 0x00800080u;
  bf16x8 zq2 = *reinterpret_cast<bf16x8*>(&zqu);

  // aug B-fragment (once): [1, 1, hi(-|zq|^2), lo(-|zq|^2), 0,0,0,0]
  bf16x8 aug_b;
  {
    float xq = -zsb[q0 + q];
    u32 xqu = __float_as_uint(xq);
    float xqh = __uint_as_float(xqu & 0xFFFF0000u);
    float xql = xq - xqh;
    u32 w1q = __builtin_amdgcn_perm(__float_as_uint(xql), xqu, 0x07060302u);
    uint4 abu = {0x3F803F80u, w1q, 0u, 0u};
    if (hi) { abu.x = 0u; abu.y = 0u; }
    aug_b = *reinterpret_cast<bf16x8*>(&abu);
  }

  // Zt A-fragment pointer: m = t, k = hi*8 + i
  const u16* zap = Zb + (size_t)(th32 + l31) * 16 + hi8;
  const float* xtp = zsb + th32 + l31;  // per-tile |zt|^2 source
  // VT B-fragment pointers: n = d, k = t
  const u16* vbp0 = VTb + (size_t)l31 * 2048 + th32 + hi8;
  const u16* vbp1 = VTb + (size_t)(32 + l31) * 2048 + th32 + hi8;

  f32x16 oacc0 = {}, oacc1 = {};
  f32x4 psacc = {};

  // tile-0 prefetch
  bf16x8 zA_c = *reinterpret_cast<const bf16x8*>(zap);
  float zs_c = xtp[0];
  bf16x8 vb00_c = *reinterpret_cast<const bf16x8*>(vbp0);
  bf16x8 vb10_c = *reinterpret_cast<const bf16x8*>(vbp1);

#pragma unroll 2
  for (int tt = 0; tt < 32; ++tt) {
    const int t0 = tt << 6;
    // current-tile late V fragments (ks=1) — consumed after softmax
    bf16x8 vb01 = *reinterpret_cast<const bf16x8*>(vbp0 + t0 + 16);
    bf16x8 vb11 = *reinterpret_cast<const bf16x8*>(vbp1 + t0 + 16);
    // next-tile prefetch
    bf16x8 zA_n = zA_c, vb00_n = vb00_c, vb10_n = vb10_c;
    float zs_n = zs_c;
    if (tt < 31) {
      zA_n = *reinterpret_cast<const bf16x8*>(zap + (size_t)(t0 + 64) * 16);
      zs_n = xtp[t0 + 64];
      vb00_n = *reinterpret_cast<const bf16x8*>(vbp0 + t0 + 64);
      vb10_n = *reinterpret_cast<const bf16x8*>(vbp1 + t0 + 64);
    }

    // aug A-fragment: [hi(-|zt|^2), lo(-|zt|^2), 1, 1, 0,0,0,0]
    float xt = -zs_c;
    u32 xtu = __float_as_uint(xt);
    float xth = __uint_as_float(xtu & 0xFFFF0000u);
    float xtl = xt - xth;
    u32 w0 = __builtin_amdgcn_perm(__float_as_uint(xtl), xtu, 0x07060302u);
    uint4 aau = {w0, 0x3F803F80u, 0u, 0u};
    if (hi) { aau.x = 0u; aau.y = 0u; }
    bf16x8 aug_a = *reinterpret_cast<bf16x8*>(&aau);

    f32x16 sc = MFMA32(aug_a, aug_b, (f32x16){});  // -|zq|^2 - |zt|^2
    sc = MFMA32(zA_c, zq2, sc);                    // + 2*dot

    // p = exp2(min(g2*sc, 0)); pack pairs via v_cvt_pk_bf16_f32.
    // PK[g4*2+c] @(l31,hi) = bf16 pair for t offsets {hi4 + g4*8 + 2c, +1}
    u32 PK[8];
#pragma unroll
    for (int g4 = 0; g4 < 4; ++g4) {
      float e0 = fminf(g2 * sc[g4 * 4 + 0], 0.f);
      float e1 = fminf(g2 * sc[g4 * 4 + 1], 0.f);
      float e2 = fminf(g2 * sc[g4 * 4 + 2], 0.f);
      float e3 = fminf(g2 * sc[g4 * 4 + 3], 0.f);
      float p0 = __builtin_amdgcn_exp2f(e0);
      float p1 = __builtin_amdgcn_exp2f(e1);
      float p2 = __builtin_amdgcn_exp2f(e2);
      float p3 = __builtin_amdgcn_exp2f(e3);
      psacc[0] += p0; psacc[1] += p1; psacc[2] += p2; psacc[3] += p3;
      asm("v_cvt_pk_bf16_f32 %0, %1, %2" : "=v"(PK[g4 * 2 + 0]) : "v"(p0), "v"(p1));
      asm("v_cvt_pk_bf16_f32 %0, %1, %2" : "=v"(PK[g4 * 2 + 1]) : "v"(p2), "v"(p3));
    }

    // Redistribute P into PV A-fragments with permlane32_swap (lane <-> lane^32):
    //   swap(PK0,PK2) -> frag0.v0 (t{0,1}/{8,9}),  frag0.v2 (t{4,5}/{12,13})
    //   swap(PK1,PK3) -> frag0.v1, frag0.v3 ; swap(PK4,PK6)/(PK5,PK7) -> frag1
    asm("v_permlane32_swap_b32 %0, %1" : "+v"(PK[0]), "+v"(PK[2]));
    asm("v_permlane32_swap_b32 %0, %1" : "+v"(PK[1]), "+v"(PK[3]));
    asm("v_permlane32_swap_b32 %0, %1" : "+v"(PK[4]), "+v"(PK[6]));
    asm("v_permlane32_swap_b32 %0, %1" : "+v"(PK[5]), "+v"(PK[7]));
    uint4 pa0u = {PK[0], PK[1], PK[2], PK[3]};
    uint4 pa1u = {PK[4], PK[5], PK[6], PK[7]};
    bf16x8 pa0 = *reinterpret_cast<bf16x8*>(&pa0u);
    bf16x8 pa1 = *reinterpret_cast<bf16x8*>(&pa1u);

    oacc0 = MFMA32(pa0, vb00_c, oacc0);
    oacc1 = MFMA32(pa0, vb10_c, oacc1);
    oacc0 = MFMA32(pa1, vb01, oacc0);
    oacc1 = MFMA32(pa1, vb11, oacc1);

    zA_c = zA_n; zs_c = zs_n; vb00_c = vb00_n; vb10_c = vb10_n;
  }

  float psum = (psacc[0] + psacc[1]) + (psacc[2] + psacc[3]);

  // merge t-halves: waves 2,3 spill oacc+psum; waves 0,1 reduce and write O
  psum += __shfl_xor(psum, 32, 64);
  __syncthreads();
  if (w >= 2) {
    char* dst = smem + (w - 2) * 8192 + lane * 16;
#pragma unroll
    for (int c = 0; c < 4; ++c) {
      f32x4 v = {oacc0[c * 4 + 0], oacc0[c * 4 + 1], oacc0[c * 4 + 2], oacc0[c * 4 + 3]};
      *reinterpret_cast<f32x4*>(dst + c * 1024) = v;
    }
#pragma unroll
    for (int c = 0; c < 4; ++c) {
      f32x4 v = {oacc1[c * 4 + 0], oacc1[c * 4 + 1], oacc1[c * 4 + 2], oacc1[c * 4 + 3]};
      *reinterpret_cast<f32x4*>(dst + (c + 4) * 1024) = v;
    }
  }
  if (lane < 32) psqf[w * 32 + l31] = psum;
  __syncthreads();
  if (w < 2) {
    const char* src = smem + w * 8192 + lane * 16;
#pragma unroll
    for (int c = 0; c < 4; ++c) {
      f32x4 v = *reinterpret_cast<const f32x4*>(src + c * 1024);
      oacc0[c * 4 + 0] += v[0]; oacc0[c * 4 + 1] += v[1];
      oacc0[c * 4 + 2] += v[2]; oacc0[c * 4 + 3] += v[3];
    }
#pragma unroll
    for (int c = 0; c < 4; ++c) {
      f32x4 v = *reinterpret_cast<const f32x4*>(src + (c + 4) * 1024);
      oacc1[c * 4 + 0] += v[0]; oacc1[c * 4 + 1] += v[1];
      oacc1[c * 4 + 2] += v[2]; oacc1[c * 4 + 3] += v[3];
    }
#pragma unroll
    for (int g4 = 0; g4 < 4; ++g4) {
      f32x4 a = *reinterpret_cast<const f32x4*>(&psqf[qh * 32 + (g4 << 3) + hi4]);
      f32x4 b2 = *reinterpret_cast<const f32x4*>(&psqf[(qh + 2) * 32 + (g4 << 3) + hi4]);
#pragma unroll
      for (int j = 0; j < 4; ++j) {
        float inv = __builtin_amdgcn_rcpf(a[j] + b2[j]);
        int qrow = (g4 << 3) + hi4 + j;
        int srow = q0 + (qh << 5) + qrow;
        u16* orow = O + ((size_t)(bb * 2048 + srow) << 10) + h * 64 + l31;
        orow[0] = f2b(oacc0[g4 * 4 + j] * inv);
        orow[32] = f2b(oacc1[g4 * 4 + j] * inv);
      }
    }
  }
}

// ---------- updated_coords = coords @ Wn + bn (fp32) ----------
__global__ void k_coords(const float* __restrict__ C, const float* __restrict__ Wn,
                         const float* __restrict__ bn, float* __restrict__ out) {
  int gid = blockIdx.x * 256 + threadIdx.x;  // 262144
  int bs = gid >> 6, c = gid & 63;
  const float* crow = C + (size_t)bs * 64;
  float acc = bn[c];
#pragma unroll 8
  for (int k = 0; k < 64; ++k) acc = fmaf(crow[k], Wn[k * 64 + c], acc);
  out[gid] = acc;
}

extern "C" void kernel_launch(void* const* d_in, const int* in_sizes, int n_in,
                              void* d_out, int out_size, void* d_ws, size_t ws_size,
                              hipStream_t stream) {
  const float* hs     = (const float*)d_in[0];
  const float* coords = (const float*)d_in[1];
  const float* Wv     = (const float*)d_in[2];
  const float* bv     = (const float*)d_in[3];
  const float* Wc     = (const float*)d_in[4];
  const float* bc     = (const float*)d_in[5];
  const float* Wn     = (const float*)d_in[6];
  const float* bn     = (const float*)d_in[7];
  const float* Wo     = (const float*)d_in[8];
  const float* bo     = (const float*)d_in[9];
  const float* gamma  = (const float*)d_in[10];
  float* out_h = (float*)d_out;
  float* out_c = out_h + 4194304;

  char* ws = (char*)d_ws;
  u16*   HSb  = (u16*)(ws + 0);          // 8 MB   (reused as O after gemm1)
  u16*   O    = (u16*)(ws + 0);
  u16*   WvT  = (u16*)(ws + 8388608);    // 2 MB
  u16*   WoT  = (u16*)(ws + 10485760);   // 2 MB
  u16*   Zw   = (u16*)(ws + 12582912);   // 2 MB
  float* zsqw = (float*)(ws + 14680064); // 0.25 MB
  u16*   Vw   = (u16*)(ws + 14942208);   // 8 MB
  u16*   VTw  = (u16*)(ws + 23330816);   // 8 MB  -> total 31.7 MB

  k_cvt<<<4096, 256, 0, stream>>>(hs, HSb, 4194304);
  k_wT<<<256, 256, 0, stream>>>(Wv, WvT);
  k_wT<<<256, 256, 0, stream>>>(Wo, WoT);
  k_z<<<256, 256, 0, stream>>>(coords, Wc, bc, Zw, zsqw);
  k_gemm<1><<<512, 256, 0, stream>>>(HSb, WvT, bv, Vw, 4096, 1024, 1024);
  k_vT<<<1024, 256, 0, stream>>>(Vw, VTw);
  k_attn<<<1024, 256, 0, stream>>>(Zw, zsqw, VTw, gamma, O);
  k_gemm<0><<<512, 256, 0, stream>>>(O, WoT, bo, out_h, 4096, 1024, 1024);
  k_coords<<<1024, 256, 0, stream>>>(coords, Wn, bn, out_c);
}

// Round 7
// 132.840 us; speedup vs baseline: 1.3015x; 1.3015x over previous
//
#include <hip/hip_runtime.h>
#include <hip/hip_bf16.h>

typedef short bf16x8 __attribute__((ext_vector_type(8)));
typedef float f32x4 __attribute__((ext_vector_type(4)));
typedef float f32x16 __attribute__((ext_vector_type(16)));
typedef unsigned short u16;
typedef unsigned int u32;

__device__ __forceinline__ u16 f2b(float f) {
  __hip_bfloat16 h = __float2bfloat16(f);
  return *reinterpret_cast<u16*>(&h);
}

#define MFMA16(a, b, c) __builtin_amdgcn_mfma_f32_16x16x32_bf16((a), (b), (c), 0, 0, 0)
#define MFMA32(a, b, c) __builtin_amdgcn_mfma_f32_32x32x16_bf16((a), (b), (c), 0, 0, 0)

// B=2 S=2048 D=1024 H=16 DC=64 HC=16 HD=64

// ---------- fp32 -> bf16 elementwise (n multiple of 1024) ----------
__global__ void k_cvt(const float* __restrict__ in, u16* __restrict__ out, int n) {
  int i = (blockIdx.x * 256 + threadIdx.x) * 4;
  if (i >= n) return;
  float4 v = *reinterpret_cast<const float4*>(in + i);
  ushort4 o;
  o.x = f2b(v.x); o.y = f2b(v.y); o.z = f2b(v.z); o.w = f2b(v.w);
  *reinterpret_cast<ushort4*>(out + i) = o;
}

// ---------- transpose + convert 1024x1024 fp32 weight -> bf16 W^T ----------
__global__ void k_wT(const float* __restrict__ W, u16* __restrict__ WT) {
  __shared__ float t[64][65];
  int tid = threadIdx.x;
  int r0 = (blockIdx.x & 15) << 6;   // k-tile
  int c0 = (blockIdx.x >> 4) << 6;   // n-tile
#pragma unroll
  for (int rep = 0; rep < 4; ++rep) {
    int e = tid + rep * 256;
    int r = e >> 4, c4 = (e & 15) << 2;
    float4 v = *reinterpret_cast<const float4*>(W + (size_t)(r0 + r) * 1024 + c0 + c4);
    t[r][c4] = v.x; t[r][c4 + 1] = v.y; t[r][c4 + 2] = v.z; t[r][c4 + 3] = v.w;
  }
  __syncthreads();
#pragma unroll
  for (int rep = 0; rep < 4; ++rep) {
    int e = tid + rep * 256;
    int c = e >> 4, r4 = (e & 15) << 2;
    ushort4 o;
    o.x = f2b(t[r4][c]); o.y = f2b(t[r4 + 1][c]);
    o.z = f2b(t[r4 + 2][c]); o.w = f2b(t[r4 + 3][c]);
    *reinterpret_cast<ushort4*>(WT + (size_t)(c0 + c) * 1024 + r0 + r4) = o;
  }
}

// ---------- z = coords @ Wc + bc ; Z bf16 [BH][S][16], zsq fp32 [BH][S] ----------
__global__ void k_z(const float* __restrict__ C, const float* __restrict__ Wc,
                    const float* __restrict__ bc, u16* __restrict__ Z,
                    float* __restrict__ zsq) {
  int gid = blockIdx.x * 256 + threadIdx.x;  // 65536 = (B*S)*H
  int bs = gid >> 4, h = gid & 15;
  const float* crow = C + (size_t)bs * 64;
  float acc[16];
#pragma unroll
  for (int c = 0; c < 16; ++c) acc[c] = bc[h * 16 + c];
  for (int k = 0; k < 64; ++k) {
    float cv = crow[k];
    const float* wr = Wc + (size_t)k * 256 + h * 16;
#pragma unroll
    for (int c = 0; c < 16; ++c) acc[c] = fmaf(cv, wr[c], acc[c]);
  }
  float sq = 0.f;
  u16 tmp[16];
#pragma unroll
  for (int c = 0; c < 16; ++c) { sq += acc[c] * acc[c]; tmp[c] = f2b(acc[c]); }
  int b = bs >> 11, s = bs & 2047;
  int bh = (b << 4) + h;
  u16* zr = Z + (((size_t)bh << 11) + s) * 16;
  *reinterpret_cast<uint4*>(zr) = *reinterpret_cast<uint4*>(tmp);
  *reinterpret_cast<uint4*>(zr + 8) = *reinterpret_cast<uint4*>(tmp + 8);
  zsq[((size_t)bh << 11) + s] = sq;
}

// ---------- GEMM C = A(bf16 MxK) * B(bf16, given as B^T NxK) + bias ----------
template <int OUTM>
__global__ __launch_bounds__(256) void k_gemm(const u16* __restrict__ A,
                                              const u16* __restrict__ BT,
                                              const float* __restrict__ bias,
                                              void* __restrict__ Cout,
                                              int M, int N, int K) {
  __shared__ u16 As[128][40];
  __shared__ u16 Bs[64][40];
  int nbn = N >> 6;
  int bm = blockIdx.x / nbn, bn = blockIdx.x % nbn;
  int tid = threadIdx.x, lane = tid & 63, w = tid >> 6;
  int wm = w >> 1, wn = w & 1;
  int l15 = lane & 15, lg = lane >> 4;
  f32x4 zero = {0.f, 0.f, 0.f, 0.f};
  f32x4 acc[4][2];
#pragma unroll
  for (int mi = 0; mi < 4; ++mi)
#pragma unroll
    for (int ni = 0; ni < 2; ++ni) acc[mi][ni] = zero;

  int ar = tid >> 2, aq = (tid & 3) << 3;
  const u16* Abase = A + (size_t)(bm * 128) * K;
  const u16* Bbase = BT + (size_t)(bn * 64) * K;

  for (int kk = 0; kk < K; kk += 32) {
    __syncthreads();
    *reinterpret_cast<uint4*>(&As[ar][aq]) =
        *reinterpret_cast<const uint4*>(Abase + (size_t)ar * K + kk + aq);
    *reinterpret_cast<uint4*>(&As[ar + 64][aq]) =
        *reinterpret_cast<const uint4*>(Abase + (size_t)(ar + 64) * K + kk + aq);
    *reinterpret_cast<uint4*>(&Bs[ar][aq]) =
        *reinterpret_cast<const uint4*>(Bbase + (size_t)ar * K + kk + aq);
    __syncthreads();
    bf16x8 af[4], bfr[2];
#pragma unroll
    for (int mi = 0; mi < 4; ++mi)
      af[mi] = *reinterpret_cast<const bf16x8*>(&As[wm * 64 + mi * 16 + l15][lg * 8]);
#pragma unroll
    for (int ni = 0; ni < 2; ++ni)
      bfr[ni] = *reinterpret_cast<const bf16x8*>(&Bs[wn * 32 + ni * 16 + l15][lg * 8]);
#pragma unroll
    for (int mi = 0; mi < 4; ++mi)
#pragma unroll
      for (int ni = 0; ni < 2; ++ni)
        acc[mi][ni] = MFMA16(af[mi], bfr[ni], acc[mi][ni]);
  }
#pragma unroll
  for (int mi = 0; mi < 4; ++mi) {
#pragma unroll
    for (int ni = 0; ni < 2; ++ni) {
      int col = bn * 64 + wn * 32 + ni * 16 + l15;
      float bb = bias[col];
#pragma unroll
      for (int j = 0; j < 4; ++j) {
        int row = bm * 128 + wm * 64 + mi * 16 + lg * 4 + j;
        float v = acc[mi][ni][j] + bb;
        if (OUTM == 0) {
          reinterpret_cast<float*>(Cout)[(size_t)row * N + col] = v;
        } else {
          int b = row >> 11, s = row & 2047, h = col >> 6, hd = col & 63;
          reinterpret_cast<u16*>(Cout)[((((size_t)(b * 16 + h) << 11) | s) << 6) + hd] = f2b(v);
        }
      }
    }
  }
}

// ---------- V [BH][S][64] -> fragment-ready VF ----------
// VF[bh][tg=0..127][dh=0..1][lane=0..63][j=0..7] (bf16), where for
// lane = hi*32 + l31: VF[...][lane][j] = V[tg*16 + hi*8 + j][dh*32 + l31].
// PV B-fragment loads in k_attn become fully coalesced 1KB wave reads.
__global__ void k_vF(const u16* __restrict__ V, u16* __restrict__ VF) {
  __shared__ u16 t[64][72];
  int tid = threadIdx.x;
  int bh = blockIdx.x >> 5;
  int s0 = (blockIdx.x & 31) << 6;
#pragma unroll
  for (int rep = 0; rep < 2; ++rep) {
    int e = tid + rep * 256;
    int sl = e >> 3, seg = (e & 7) << 3;
    *reinterpret_cast<uint4*>(&t[sl][seg]) =
        *reinterpret_cast<const uint4*>(V + ((size_t)(bh * 2048 + s0 + sl) << 6) + seg);
  }
  __syncthreads();
  int tg0 = (blockIdx.x & 31) << 2;
#pragma unroll
  for (int rep = 0; rep < 2; ++rep) {
    int c = tid + rep * 256;          // 512 chunks of 16B
    int l = c & 63;
    int dh = (c >> 6) & 1;
    int tgl = c >> 7;                 // 0..3
    int l31 = l & 31, hi = l >> 5;
    u16 tmp[8];
#pragma unroll
    for (int j = 0; j < 8; ++j) tmp[j] = t[tgl * 16 + hi * 8 + j][dh * 32 + l31];
    size_t off = ((((size_t)bh * 128 + tg0 + tgl) * 2 + dh) << 9) + (l << 3);
    *reinterpret_cast<uint4*>(VF + off) = *reinterpret_cast<uint4*>(tmp);
  }
}

// ---------- flash attention over gravity scores ----------
// sc = 2*dot - |zq|^2 - |zt|^2 entirely in MFMA (aug fragments).
// p = exp2(min(g2*sc,0)); P staged via per-wave LDS scratch (same-wave
// write->read). V fragments from coalesced VF layout. No barriers in loop.
__global__ __launch_bounds__(256, 4) void k_attn(const u16* __restrict__ Z,
                                                 const float* __restrict__ zsq,
                                                 const u16* __restrict__ VF,
                                                 const float* __restrict__ gamma,
                                                 u16* __restrict__ O) {
  // smem: [0,9216) P rows 144B x 64 (XOR-swizzled); [17408,17920) psq[4][32].
  // End-phase oacc spill reuses [0,16384).
  __shared__ __align__(16) char smem[17920];
  float* psqf = reinterpret_cast<float*>(smem + 17408);

  int tid = threadIdx.x, lane = tid & 63, w = tid >> 6;
  int l31 = lane & 31, hi = lane >> 5;
  int hi4 = hi << 2, hi8 = hi << 3;
  int th = w >> 1, qh = w & 1, th32 = th << 5;
  int bh = blockIdx.x >> 5, qt = blockIdx.x & 31;
  int q0 = qt << 6;
  int h = bh & 15, bb = bh >> 4;
  float gm = gamma[h];
  float g = (gm > 15.f) ? gm : log1pf(__expf(gm));  // softplus
  float g2 = g * 1.4426950408889634f;               // fold log2(e) -> exp2

  const u16* Zb = Z + ((size_t)bh << 11) * 16;
  const float* zsb = zsq + ((size_t)bh << 11);
  const u16* VFb = VF + ((size_t)bh << 17);

  int q = (qh << 5) + l31;              // this lane's q (local to 64-tile)
  char* Prow = smem + q * 144;
  u32 psw = ((u32)(q >> 3) & 3u) << 4;  // XOR swizzle within 64B half

  // Q B-fragment, pre-doubled: bf16 *2 == exponent+1 (exact for normals)
  uint4 zqu = *reinterpret_cast<const uint4*>(Zb + (size_t)(q0 + q) * 16 + hi8);
  zqu.x += 0x00800080u; zqu.y += 0x00800080u;
  zqu.z += 0x00800080u; zqu.w += 0x00800080u;
  bf16x8 zq2 = *reinterpret_cast<bf16x8*>(&zqu);

  // aug B-fragment (once): [1, 1, hi(-|zq|^2), lo(-|zq|^2), 0,0,0,0]
  bf16x8 aug_b;
  {
    float xq = -zsb[q0 + q];
    u32 xqu = __float_as_uint(xq);
    float xqh = __uint_as_float(xqu & 0xFFFF0000u);
    float xql = xq - xqh;
    u32 w1q = __builtin_amdgcn_perm(__float_as_uint(xql), xqu, 0x07060302u);
    uint4 abu = {0x3F803F80u, w1q, 0u, 0u};
    if (hi) { abu.x = 0u; abu.y = 0u; }
    aug_b = *reinterpret_cast<bf16x8*>(&abu);
  }

  // Zt A-fragment pointer: m = t, k = hi*8 + i
  const u16* zap = Zb + (size_t)(th32 + l31) * 16 + hi8;
  const float* xtp = zsb + th32 + l31;  // per-tile |zt|^2 source
  // VF fragment base for this wave (tg = tt*4 + th*2): coalesced lane*16B
  const u16* vwp = VFb + ((size_t)(th * 2) << 10) + (lane << 3);

  f32x16 oacc0 = {}, oacc1 = {};
  f32x4 psacc = {};

  // tile-0 prefetch
  bf16x8 zA_c = *reinterpret_cast<const bf16x8*>(zap);
  float zs_c = xtp[0];
  bf16x8 vb00_c = *reinterpret_cast<const bf16x8*>(vwp);
  bf16x8 vb10_c = *reinterpret_cast<const bf16x8*>(vwp + 512);

#pragma unroll 2
  for (int tt = 0; tt < 32; ++tt) {
    const int t0 = tt << 6;
    const u16* vtb = vwp + (tt << 12);
    // current-tile late V fragments (tg+1) — consumed after softmax
    bf16x8 vb01 = *reinterpret_cast<const bf16x8*>(vtb + 1024);
    bf16x8 vb11 = *reinterpret_cast<const bf16x8*>(vtb + 1024 + 512);
    // next-tile prefetch
    bf16x8 zA_n = zA_c, vb00_n = vb00_c, vb10_n = vb10_c;
    float zs_n = zs_c;
    if (tt < 31) {
      zA_n = *reinterpret_cast<const bf16x8*>(zap + (size_t)(t0 + 64) * 16);
      zs_n = xtp[t0 + 64];
      vb00_n = *reinterpret_cast<const bf16x8*>(vtb + 4096);
      vb10_n = *reinterpret_cast<const bf16x8*>(vtb + 4096 + 512);
    }

    // aug A-fragment: [hi(-|zt|^2), lo(-|zt|^2), 1, 1, 0,0,0,0]
    float xt = -zs_c;
    u32 xtu = __float_as_uint(xt);
    float xth = __uint_as_float(xtu & 0xFFFF0000u);
    float xtl = xt - xth;
    u32 w0 = __builtin_amdgcn_perm(__float_as_uint(xtl), xtu, 0x07060302u);
    uint4 aau = {w0, 0x3F803F80u, 0u, 0u};
    if (hi) { aau.x = 0u; aau.y = 0u; }
    bf16x8 aug_a = *reinterpret_cast<bf16x8*>(&aau);

    f32x16 sc = MFMA32(aug_a, aug_b, (f32x16){});  // -|zq|^2 - |zt|^2
    sc = MFMA32(zA_c, zq2, sc);                    // + 2*dot

    // p = exp2(min(g2*sc, 0)); pack RTE via v_cvt_pk_bf16_f32
#pragma unroll
    for (int g4 = 0; g4 < 4; ++g4) {
      float e0 = fminf(g2 * sc[g4 * 4 + 0], 0.f);
      float e1 = fminf(g2 * sc[g4 * 4 + 1], 0.f);
      float e2 = fminf(g2 * sc[g4 * 4 + 2], 0.f);
      float e3 = fminf(g2 * sc[g4 * 4 + 3], 0.f);
      float p0 = __builtin_amdgcn_exp2f(e0);
      float p1 = __builtin_amdgcn_exp2f(e1);
      float p2 = __builtin_amdgcn_exp2f(e2);
      float p3 = __builtin_amdgcn_exp2f(e3);
      psacc[0] += p0; psacc[1] += p1; psacc[2] += p2; psacc[3] += p3;
      u32 pk0, pk1;
      asm("v_cvt_pk_bf16_f32 %0, %1, %2" : "=v"(pk0) : "v"(p0), "v"(p1));
      asm("v_cvt_pk_bf16_f32 %0, %1, %2" : "=v"(pk1) : "v"(p2), "v"(p3));
      uint2 pkv = {pk0, pk1};
      int tcol = th32 + (g4 << 3) + hi4;
      *reinterpret_cast<uint2*>(Prow + (((u32)(tcol << 1)) ^ psw)) = pkv;
    }

    // PV A-fragments from own P quadrant (same-wave LDS write->read, in-order)
    bf16x8 pa0 = *reinterpret_cast<const bf16x8*>(Prow + (((u32)((th32 + hi8) << 1)) ^ psw));
    bf16x8 pa1 = *reinterpret_cast<const bf16x8*>(Prow + (((u32)((th32 + 16 + hi8) << 1)) ^ psw));

    oacc0 = MFMA32(pa0, vb00_c, oacc0);
    oacc1 = MFMA32(pa0, vb10_c, oacc1);
    oacc0 = MFMA32(pa1, vb01, oacc0);
    oacc1 = MFMA32(pa1, vb11, oacc1);

    zA_c = zA_n; zs_c = zs_n; vb00_c = vb00_n; vb10_c = vb10_n;
  }

  float psum = (psacc[0] + psacc[1]) + (psacc[2] + psacc[3]);

  // merge t-halves: waves 2,3 spill oacc+psum; waves 0,1 reduce and write O
  psum += __shfl_xor(psum, 32, 64);
  __syncthreads();
  if (w >= 2) {
    char* dst = smem + (w - 2) * 8192 + lane * 16;
#pragma unroll
    for (int c = 0; c < 4; ++c) {
      f32x4 v = {oacc0[c * 4 + 0], oacc0[c * 4 + 1], oacc0[c * 4 + 2], oacc0[c * 4 + 3]};
      *reinterpret_cast<f32x4*>(dst + c * 1024) = v;
    }
#pragma unroll
    for (int c = 0; c < 4; ++c) {
      f32x4 v = {oacc1[c * 4 + 0], oacc1[c * 4 + 1], oacc1[c * 4 + 2], oacc1[c * 4 + 3]};
      *reinterpret_cast<f32x4*>(dst + (c + 4) * 1024) = v;
    }
  }
  if (lane < 32) psqf[w * 32 + l31] = psum;
  __syncthreads();
  if (w < 2) {
    const char* src = smem + w * 8192 + lane * 16;
#pragma unroll
    for (int c = 0; c < 4; ++c) {
      f32x4 v = *reinterpret_cast<const f32x4*>(src + c * 1024);
      oacc0[c * 4 + 0] += v[0]; oacc0[c * 4 + 1] += v[1];
      oacc0[c * 4 + 2] += v[2]; oacc0[c * 4 + 3] += v[3];
    }
#pragma unroll
    for (int c = 0; c < 4; ++c) {
      f32x4 v = *reinterpret_cast<const f32x4*>(src + (c + 4) * 1024);
      oacc1[c * 4 + 0] += v[0]; oacc1[c * 4 + 1] += v[1];
      oacc1[c * 4 + 2] += v[2]; oacc1[c * 4 + 3] += v[3];
    }
#pragma unroll
    for (int g4 = 0; g4 < 4; ++g4) {
      f32x4 a = *reinterpret_cast<const f32x4*>(&psqf[qh * 32 + (g4 << 3) + hi4]);
      f32x4 b2 = *reinterpret_cast<const f32x4*>(&psqf[(qh + 2) * 32 + (g4 << 3) + hi4]);
#pragma unroll
      for (int j = 0; j < 4; ++j) {
        float inv = __builtin_amdgcn_rcpf(a[j] + b2[j]);
        int qrow = (g4 << 3) + hi4 + j;
        int srow = q0 + (qh << 5) + qrow;
        u16* orow = O + ((size_t)(bb * 2048 + srow) << 10) + h * 64 + l31;
        orow[0] = f2b(oacc0[g4 * 4 + j] * inv);
        orow[32] = f2b(oacc1[g4 * 4 + j] * inv);
      }
    }
  }
}

// ---------- updated_coords = coords @ Wn + bn (fp32) ----------
__global__ void k_coords(const float* __restrict__ C, const float* __restrict__ Wn,
                         const float* __restrict__ bn, float* __restrict__ out) {
  int gid = blockIdx.x * 256 + threadIdx.x;  // 262144
  int bs = gid >> 6, c = gid & 63;
  const float* crow = C + (size_t)bs * 64;
  float acc = bn[c];
#pragma unroll 8
  for (int k = 0; k < 64; ++k) acc = fmaf(crow[k], Wn[k * 64 + c], acc);
  out[gid] = acc;
}

extern "C" void kernel_launch(void* const* d_in, const int* in_sizes, int n_in,
                              void* d_out, int out_size, void* d_ws, size_t ws_size,
                              hipStream_t stream) {
  const float* hs     = (const float*)d_in[0];
  const float* coords = (const float*)d_in[1];
  const float* Wv     = (const float*)d_in[2];
  const float* bv     = (const float*)d_in[3];
  const float* Wc     = (const float*)d_in[4];
  const float* bc     = (const float*)d_in[5];
  const float* Wn     = (const float*)d_in[6];
  const float* bn     = (const float*)d_in[7];
  const float* Wo     = (const float*)d_in[8];
  const float* bo     = (const float*)d_in[9];
  const float* gamma  = (const float*)d_in[10];
  float* out_h = (float*)d_out;
  float* out_c = out_h + 4194304;

  char* ws = (char*)d_ws;
  u16*   HSb  = (u16*)(ws + 0);          // 8 MB   (reused as O after gemm1)
  u16*   O    = (u16*)(ws + 0);
  u16*   WvT  = (u16*)(ws + 8388608);    // 2 MB
  u16*   WoT  = (u16*)(ws + 10485760);   // 2 MB
  u16*   Zw   = (u16*)(ws + 12582912);   // 2 MB
  float* zsqw = (float*)(ws + 14680064); // 0.25 MB
  u16*   Vw   = (u16*)(ws + 14942208);   // 8 MB
  u16*   VFw  = (u16*)(ws + 23330816);   // 8 MB  -> total 31.7 MB

  k_cvt<<<4096, 256, 0, stream>>>(hs, HSb, 4194304);
  k_wT<<<256, 256, 0, stream>>>(Wv, WvT);
  k_wT<<<256, 256, 0, stream>>>(Wo, WoT);
  k_z<<<256, 256, 0, stream>>>(coords, Wc, bc, Zw, zsqw);
  k_gemm<1><<<512, 256, 0, stream>>>(HSb, WvT, bv, Vw, 4096, 1024, 1024);
  k_vF<<<1024, 256, 0, stream>>>(Vw, VFw);
  k_attn<<<1024, 256, 0, stream>>>(Zw, zsqw, VFw, gamma, O);
  k_gemm<0><<<512, 256, 0, stream>>>(O, WoT, bo, out_h, 4096, 1024, 1024);
  k_coords<<<1024, 256, 0, stream>>>(coords, Wn, bn, out_c);
}

// Round 8
// 121.318 us; speedup vs baseline: 1.4251x; 1.0950x over previous
//
#include <hip/hip_runtime.h>
#include <hip/hip_bf16.h>

typedef short bf16x8 __attribute__((ext_vector_type(8)));
typedef float f32x4 __attribute__((ext_vector_type(4)));
typedef float f32x16 __attribute__((ext_vector_type(16)));
typedef unsigned short u16;
typedef unsigned int u32;

__device__ __forceinline__ u16 f2b(float f) {
  __hip_bfloat16 h = __float2bfloat16(f);
  return *reinterpret_cast<u16*>(&h);
}

#define MFMA16(a, b, c) __builtin_amdgcn_mfma_f32_16x16x32_bf16((a), (b), (c), 0, 0, 0)
#define MFMA32(a, b, c) __builtin_amdgcn_mfma_f32_32x32x16_bf16((a), (b), (c), 0, 0, 0)

// B=2 S=2048 D=1024 H=16 DC=64 HC=16 HD=64

// ---------- fp32 -> bf16 elementwise (n multiple of 1024) ----------
__global__ void k_cvt(const float* __restrict__ in, u16* __restrict__ out, int n) {
  int i = (blockIdx.x * 256 + threadIdx.x) * 4;
  if (i >= n) return;
  float4 v = *reinterpret_cast<const float4*>(in + i);
  ushort4 o;
  o.x = f2b(v.x); o.y = f2b(v.y); o.z = f2b(v.z); o.w = f2b(v.w);
  *reinterpret_cast<ushort4*>(out + i) = o;
}

// ---------- transpose + convert 1024x1024 fp32 weight -> bf16 W^T ----------
__global__ void k_wT(const float* __restrict__ W, u16* __restrict__ WT) {
  __shared__ float t[64][65];
  int tid = threadIdx.x;
  int r0 = (blockIdx.x & 15) << 6;   // k-tile
  int c0 = (blockIdx.x >> 4) << 6;   // n-tile
#pragma unroll
  for (int rep = 0; rep < 4; ++rep) {
    int e = tid + rep * 256;
    int r = e >> 4, c4 = (e & 15) << 2;
    float4 v = *reinterpret_cast<const float4*>(W + (size_t)(r0 + r) * 1024 + c0 + c4);
    t[r][c4] = v.x; t[r][c4 + 1] = v.y; t[r][c4 + 2] = v.z; t[r][c4 + 3] = v.w;
  }
  __syncthreads();
#pragma unroll
  for (int rep = 0; rep < 4; ++rep) {
    int e = tid + rep * 256;
    int c = e >> 4, r4 = (e & 15) << 2;
    ushort4 o;
    o.x = f2b(t[r4][c]); o.y = f2b(t[r4 + 1][c]);
    o.z = f2b(t[r4 + 2][c]); o.w = f2b(t[r4 + 3][c]);
    *reinterpret_cast<ushort4*>(WT + (size_t)(c0 + c) * 1024 + r0 + r4) = o;
  }
}

// ---------- z = coords @ Wc + bc ; Z bf16 [BH][S][16], zsq fp32 [BH][S] ----------
__global__ void k_z(const float* __restrict__ C, const float* __restrict__ Wc,
                    const float* __restrict__ bc, u16* __restrict__ Z,
                    float* __restrict__ zsq) {
  int gid = blockIdx.x * 256 + threadIdx.x;  // 65536 = (B*S)*H
  int bs = gid >> 4, h = gid & 15;
  const float* crow = C + (size_t)bs * 64;
  float acc[16];
#pragma unroll
  for (int c = 0; c < 16; ++c) acc[c] = bc[h * 16 + c];
  for (int k = 0; k < 64; ++k) {
    float cv = crow[k];
    const float* wr = Wc + (size_t)k * 256 + h * 16;
#pragma unroll
    for (int c = 0; c < 16; ++c) acc[c] = fmaf(cv, wr[c], acc[c]);
  }
  float sq = 0.f;
  u16 tmp[16];
#pragma unroll
  for (int c = 0; c < 16; ++c) { sq += acc[c] * acc[c]; tmp[c] = f2b(acc[c]); }
  int b = bs >> 11, s = bs & 2047;
  int bh = (b << 4) + h;
  u16* zr = Z + (((size_t)bh << 11) + s) * 16;
  *reinterpret_cast<uint4*>(zr) = *reinterpret_cast<uint4*>(tmp);
  *reinterpret_cast<uint4*>(zr + 8) = *reinterpret_cast<uint4*>(tmp + 8);
  zsq[((size_t)bh << 11) + s] = sq;
}

// ---------- GEMM C = A(bf16 MxK) * B(bf16, given as B^T NxK) + bias ----------
// m97-style: BK=64, global_load_lds width=16 staging, linear LDS with
// XOR chunk swizzle (chunk ^= row&7) applied on BOTH source and read sides.
template <int OUTM>
__global__ __launch_bounds__(256) void k_gemm(const u16* __restrict__ A,
                                              const u16* __restrict__ BT,
                                              const float* __restrict__ bias,
                                              void* __restrict__ Cout,
                                              int M, int N, int K) {
  __shared__ u16 As[128 * 64];
  __shared__ u16 Bs[64 * 64];
  int nbn = N >> 6;
  int bm = blockIdx.x / nbn, bn = blockIdx.x % nbn;
  int tid = threadIdx.x, lane = tid & 63, w = tid >> 6;
  int wm = w >> 1, wn = w & 1;
  int l15 = lane & 15, lg = lane >> 4;
  int lr = lane >> 3;        // row-within-8 for staging
  int swc = (lane & 7) ^ lr; // inverse-swizzled source chunk

  f32x4 acc[4][2];
#pragma unroll
  for (int mi = 0; mi < 4; ++mi)
#pragma unroll
    for (int ni = 0; ni < 2; ++ni) acc[mi][ni] = (f32x4){0.f, 0.f, 0.f, 0.f};

  const u16* Abase = A + (size_t)(bm * 128) * K + (size_t)(w * 8 + lr) * K + swc * 8;
  const u16* Bbase = BT + (size_t)(bn * 64) * K + (size_t)(w * 8 + lr) * K + swc * 8;
  int rsw = l15 & 7;  // read-side swizzle row bits

  for (int kk0 = 0; kk0 < K; kk0 += 64) {
    __syncthreads();
#pragma unroll
    for (int i = 0; i < 4; ++i)
      __builtin_amdgcn_global_load_lds(
          (const __attribute__((address_space(1))) u32*)(Abase + (size_t)(i * 32) * K + kk0),
          (__attribute__((address_space(3))) u32*)&As[(i * 32 + w * 8) * 64], 16, 0, 0);
#pragma unroll
    for (int i = 0; i < 2; ++i)
      __builtin_amdgcn_global_load_lds(
          (const __attribute__((address_space(1))) u32*)(Bbase + (size_t)(i * 32) * K + kk0),
          (__attribute__((address_space(3))) u32*)&Bs[(i * 32 + w * 8) * 64], 16, 0, 0);
    __syncthreads();
#pragma unroll
    for (int kk = 0; kk < 2; ++kk) {
      bf16x8 af[4], bfr[2];
#pragma unroll
      for (int mi = 0; mi < 4; ++mi) {
        int row = wm * 64 + mi * 16 + l15;
        int ch = (kk * 4 + lg) ^ rsw;
        af[mi] = *reinterpret_cast<const bf16x8*>(&As[row * 64 + ch * 8]);
      }
#pragma unroll
      for (int ni = 0; ni < 2; ++ni) {
        int row = wn * 32 + ni * 16 + l15;
        int ch = (kk * 4 + lg) ^ rsw;
        bfr[ni] = *reinterpret_cast<const bf16x8*>(&Bs[row * 64 + ch * 8]);
      }
#pragma unroll
      for (int mi = 0; mi < 4; ++mi)
#pragma unroll
        for (int ni = 0; ni < 2; ++ni)
          acc[mi][ni] = MFMA16(af[mi], bfr[ni], acc[mi][ni]);
    }
  }
#pragma unroll
  for (int mi = 0; mi < 4; ++mi) {
#pragma unroll
    for (int ni = 0; ni < 2; ++ni) {
      int col = bn * 64 + wn * 32 + ni * 16 + l15;
      float bb = bias[col];
#pragma unroll
      for (int j = 0; j < 4; ++j) {
        int row = bm * 128 + wm * 64 + mi * 16 + lg * 4 + j;
        float v = acc[mi][ni][j] + bb;
        if (OUTM == 0) {
          reinterpret_cast<float*>(Cout)[(size_t)row * N + col] = v;
        } else {
          int b = row >> 11, s = row & 2047, h = col >> 6, hd = col & 63;
          reinterpret_cast<u16*>(Cout)[((((size_t)(b * 16 + h) << 11) | s) << 6) + hd] = f2b(v);
        }
      }
    }
  }
}

// ---------- V [BH][S][64] -> fragment-ready VF ----------
// VF[bh][tg=0..127][dh=0..1][lane=0..63][j=0..7] (bf16), where for
// lane = hi*32 + l31: VF[...][lane][j] = V[tg*16 + hi*8 + j][dh*32 + l31].
__global__ void k_vF(const u16* __restrict__ V, u16* __restrict__ VF) {
  __shared__ u16 t[64][72];
  int tid = threadIdx.x;
  int bh = blockIdx.x >> 5;
  int s0 = (blockIdx.x & 31) << 6;
#pragma unroll
  for (int rep = 0; rep < 2; ++rep) {
    int e = tid + rep * 256;
    int sl = e >> 3, seg = (e & 7) << 3;
    *reinterpret_cast<uint4*>(&t[sl][seg]) =
        *reinterpret_cast<const uint4*>(V + ((size_t)(bh * 2048 + s0 + sl) << 6) + seg);
  }
  __syncthreads();
  int tg0 = (blockIdx.x & 31) << 2;
#pragma unroll
  for (int rep = 0; rep < 2; ++rep) {
    int c = tid + rep * 256;          // 512 chunks of 16B
    int l = c & 63;
    int dh = (c >> 6) & 1;
    int tgl = c >> 7;                 // 0..3
    int l31 = l & 31, hi = l >> 5;
    u16 tmp[8];
#pragma unroll
    for (int j = 0; j < 8; ++j) tmp[j] = t[tgl * 16 + hi * 8 + j][dh * 32 + l31];
    size_t off = ((((size_t)bh * 128 + tg0 + tgl) * 2 + dh) << 9) + (l << 3);
    *reinterpret_cast<uint4*>(VF + off) = *reinterpret_cast<uint4*>(tmp);
  }
}

// ---------- flash attention over gravity scores ----------
// sc = 2*dot - |zq|^2 - |zt|^2 entirely in MFMA (aug fragments).
// p = exp2(min(g2*sc,0)); P staged via per-wave LDS scratch, PING-PONGED per
// tile so tile t+1's QK/softmax can overlap tile t's PV (no LDS WAR dep).
// V fragments from coalesced VF layout. No barriers in loop.
__global__ __launch_bounds__(256, 4) void k_attn(const u16* __restrict__ Z,
                                                 const float* __restrict__ zsq,
                                                 const u16* __restrict__ VF,
                                                 const float* __restrict__ gamma,
                                                 u16* __restrict__ O) {
  // smem: [0,18432) P double buffer (2 x 64 rows x 144B, XOR-swizzled);
  // [18432,18944) psq[4][32]. End-phase oacc spill reuses [0,16384).
  __shared__ __align__(16) char smem[18944];
  float* psqf = reinterpret_cast<float*>(smem + 18432);

  int tid = threadIdx.x, lane = tid & 63, w = tid >> 6;
  int l31 = lane & 31, hi = lane >> 5;
  int hi4 = hi << 2, hi8 = hi << 3;
  int th = w >> 1, qh = w & 1, th32 = th << 5;
  int bh = blockIdx.x >> 5, qt = blockIdx.x & 31;
  int q0 = qt << 6;
  int h = bh & 15, bb = bh >> 4;
  float gm = gamma[h];
  float g = (gm > 15.f) ? gm : log1pf(__expf(gm));  // softplus
  float g2 = g * 1.4426950408889634f;               // fold log2(e) -> exp2

  const u16* Zb = Z + ((size_t)bh << 11) * 16;
  const float* zsb = zsq + ((size_t)bh << 11);
  const u16* VFb = VF + ((size_t)bh << 17);

  int q = (qh << 5) + l31;              // this lane's q (local to 64-tile)
  char* Prow = smem + q * 144;
  u32 psw = ((u32)(q >> 3) & 3u) << 4;  // XOR swizzle within 64B half

  // Q B-fragment, pre-doubled: bf16 *2 == exponent+1 (exact for normals)
  uint4 zqu = *reinterpret_cast<const uint4*>(Zb + (size_t)(q0 + q) * 16 + hi8);
  zqu.x += 0x00800080u; zqu.y += 0x00800080u;
  zqu.z += 0x00800080u; zqu.w += 0x00800080u;
  bf16x8 zq2 = *reinterpret_cast<bf16x8*>(&zqu);

  // aug B-fragment (once): [1, 1, hi(-|zq|^2), lo(-|zq|^2), 0,0,0,0]
  bf16x8 aug_b;
  {
    float xq = -zsb[q0 + q];
    u32 xqu = __float_as_uint(xq);
    float xqh = __uint_as_float(xqu & 0xFFFF0000u);
    float xql = xq - xqh;
    u32 w1q = __builtin_amdgcn_perm(__float_as_uint(xql), xqu, 0x07060302u);
    uint4 abu = {0x3F803F80u, w1q, 0u, 0u};
    if (hi) { abu.x = 0u; abu.y = 0u; }
    aug_b = *reinterpret_cast<bf16x8*>(&abu);
  }

  // Zt A-fragment pointer: m = t, k = hi*8 + i
  const u16* zap = Zb + (size_t)(th32 + l31) * 16 + hi8;
  const float* xtp = zsb + th32 + l31;  // per-tile |zt|^2 source
  // VF fragment base for this wave (tg = tt*4 + th*2): coalesced lane*16B
  const u16* vwp = VFb + ((size_t)(th * 2) << 10) + (lane << 3);

  f32x16 oacc0 = {}, oacc1 = {};
  f32x4 psacc = {};

  // tile-0 prefetch
  bf16x8 zA_c = *reinterpret_cast<const bf16x8*>(zap);
  float zs_c = xtp[0];
  bf16x8 vb00_c = *reinterpret_cast<const bf16x8*>(vwp);
  bf16x8 vb10_c = *reinterpret_cast<const bf16x8*>(vwp + 512);

#pragma unroll 2
  for (int tt = 0; tt < 32; ++tt) {
    const int t0 = tt << 6;
    char* Pr = Prow + ((tt & 1) ? 9216 : 0);
    const u16* vtb = vwp + (tt << 12);
    // current-tile late V fragments (tg+1) — consumed after softmax
    bf16x8 vb01 = *reinterpret_cast<const bf16x8*>(vtb + 1024);
    bf16x8 vb11 = *reinterpret_cast<const bf16x8*>(vtb + 1024 + 512);
    // next-tile prefetch
    bf16x8 zA_n = zA_c, vb00_n = vb00_c, vb10_n = vb10_c;
    float zs_n = zs_c;
    if (tt < 31) {
      zA_n = *reinterpret_cast<const bf16x8*>(zap + (size_t)(t0 + 64) * 16);
      zs_n = xtp[t0 + 64];
      vb00_n = *reinterpret_cast<const bf16x8*>(vtb + 4096);
      vb10_n = *reinterpret_cast<const bf16x8*>(vtb + 4096 + 512);
    }

    // aug A-fragment: [hi(-|zt|^2), lo(-|zt|^2), 1, 1, 0,0,0,0]
    float xt = -zs_c;
    u32 xtu = __float_as_uint(xt);
    float xth = __uint_as_float(xtu & 0xFFFF0000u);
    float xtl = xt - xth;
    u32 w0 = __builtin_amdgcn_perm(__float_as_uint(xtl), xtu, 0x07060302u);
    uint4 aau = {w0, 0x3F803F80u, 0u, 0u};
    if (hi) { aau.x = 0u; aau.y = 0u; }
    bf16x8 aug_a = *reinterpret_cast<bf16x8*>(&aau);

    f32x16 sc = MFMA32(aug_a, aug_b, (f32x16){});  // -|zq|^2 - |zt|^2
    sc = MFMA32(zA_c, zq2, sc);                    // + 2*dot

    // p = exp2(min(g2*sc, 0)); pack RTE via v_cvt_pk_bf16_f32
#pragma unroll
    for (int g4 = 0; g4 < 4; ++g4) {
      float e0 = fminf(g2 * sc[g4 * 4 + 0], 0.f);
      float e1 = fminf(g2 * sc[g4 * 4 + 1], 0.f);
      float e2 = fminf(g2 * sc[g4 * 4 + 2], 0.f);
      float e3 = fminf(g2 * sc[g4 * 4 + 3], 0.f);
      float p0 = __builtin_amdgcn_exp2f(e0);
      float p1 = __builtin_amdgcn_exp2f(e1);
      float p2 = __builtin_amdgcn_exp2f(e2);
      float p3 = __builtin_amdgcn_exp2f(e3);
      psacc[0] += p0; psacc[1] += p1; psacc[2] += p2; psacc[3] += p3;
      u32 pk0, pk1;
      asm("v_cvt_pk_bf16_f32 %0, %1, %2" : "=v"(pk0) : "v"(p0), "v"(p1));
      asm("v_cvt_pk_bf16_f32 %0, %1, %2" : "=v"(pk1) : "v"(p2), "v"(p3));
      uint2 pkv = {pk0, pk1};
      int tcol = th32 + (g4 << 3) + hi4;
      *reinterpret_cast<uint2*>(Pr + (((u32)(tcol << 1)) ^ psw)) = pkv;
    }

    // PV A-fragments from own P quadrant (same-wave LDS write->read, in-order)
    bf16x8 pa0 = *reinterpret_cast<const bf16x8*>(Pr + (((u32)((th32 + hi8) << 1)) ^ psw));
    bf16x8 pa1 = *reinterpret_cast<const bf16x8*>(Pr + (((u32)((th32 + 16 + hi8) << 1)) ^ psw));

    oacc0 = MFMA32(pa0, vb00_c, oacc0);
    oacc1 = MFMA32(pa0, vb10_c, oacc1);
    oacc0 = MFMA32(pa1, vb01, oacc0);
    oacc1 = MFMA32(pa1, vb11, oacc1);

    zA_c = zA_n; zs_c = zs_n; vb00_c = vb00_n; vb10_c = vb10_n;
  }

  float psum = (psacc[0] + psacc[1]) + (psacc[2] + psacc[3]);

  // merge t-halves: waves 2,3 spill oacc+psum; waves 0,1 reduce and write O
  psum += __shfl_xor(psum, 32, 64);
  __syncthreads();
  if (w >= 2) {
    char* dst = smem + (w - 2) * 8192 + lane * 16;
#pragma unroll
    for (int c = 0; c < 4; ++c) {
      f32x4 v = {oacc0[c * 4 + 0], oacc0[c * 4 + 1], oacc0[c * 4 + 2], oacc0[c * 4 + 3]};
      *reinterpret_cast<f32x4*>(dst + c * 1024) = v;
    }
#pragma unroll
    for (int c = 0; c < 4; ++c) {
      f32x4 v = {oacc1[c * 4 + 0], oacc1[c * 4 + 1], oacc1[c * 4 + 2], oacc1[c * 4 + 3]};
      *reinterpret_cast<f32x4*>(dst + (c + 4) * 1024) = v;
    }
  }
  if (lane < 32) psqf[w * 32 + l31] = psum;
  __syncthreads();
  if (w < 2) {
    const char* src = smem + w * 8192 + lane * 16;
#pragma unroll
    for (int c = 0; c < 4; ++c) {
      f32x4 v = *reinterpret_cast<const f32x4*>(src + c * 1024);
      oacc0[c * 4 + 0] += v[0]; oacc0[c * 4 + 1] += v[1];
      oacc0[c * 4 + 2] += v[2]; oacc0[c * 4 + 3] += v[3];
    }
#pragma unroll
    for (int c = 0; c < 4; ++c) {
      f32x4 v = *reinterpret_cast<const f32x4*>(src + (c + 4) * 1024);
      oacc1[c * 4 + 0] += v[0]; oacc1[c * 4 + 1] += v[1];
      oacc1[c * 4 + 2] += v[2]; oacc1[c * 4 + 3] += v[3];
    }
#pragma unroll
    for (int g4 = 0; g4 < 4; ++g4) {
      f32x4 a = *reinterpret_cast<const f32x4*>(&psqf[qh * 32 + (g4 << 3) + hi4]);
      f32x4 b2 = *reinterpret_cast<const f32x4*>(&psqf[(qh + 2) * 32 + (g4 << 3) + hi4]);
#pragma unroll
      for (int j = 0; j < 4; ++j) {
        float inv = __builtin_amdgcn_rcpf(a[j] + b2[j]);
        int qrow = (g4 << 3) + hi4 + j;
        int srow = q0 + (qh << 5) + qrow;
        u16* orow = O + ((size_t)(bb * 2048 + srow) << 10) + h * 64 + l31;
        orow[0] = f2b(oacc0[g4 * 4 + j] * inv);
        orow[32] = f2b(oacc1[g4 * 4 + j] * inv);
      }
    }
  }
}

// ---------- updated_coords = coords @ Wn + bn (fp32) ----------
__global__ void k_coords(const float* __restrict__ C, const float* __restrict__ Wn,
                         const float* __restrict__ bn, float* __restrict__ out) {
  int gid = blockIdx.x * 256 + threadIdx.x;  // 262144
  int bs = gid >> 6, c = gid & 63;
  const float* crow = C + (size_t)bs * 64;
  float acc = bn[c];
#pragma unroll 8
  for (int k = 0; k < 64; ++k) acc = fmaf(crow[k], Wn[k * 64 + c], acc);
  out[gid] = acc;
}

extern "C" void kernel_launch(void* const* d_in, const int* in_sizes, int n_in,
                              void* d_out, int out_size, void* d_ws, size_t ws_size,
                              hipStream_t stream) {
  const float* hs     = (const float*)d_in[0];
  const float* coords = (const float*)d_in[1];
  const float* Wv     = (const float*)d_in[2];
  const float* bv     = (const float*)d_in[3];
  const float* Wc     = (const float*)d_in[4];
  const float* bc     = (const float*)d_in[5];
  const float* Wn     = (const float*)d_in[6];
  const float* bn     = (const float*)d_in[7];
  const float* Wo     = (const float*)d_in[8];
  const float* bo     = (const float*)d_in[9];
  const float* gamma  = (const float*)d_in[10];
  float* out_h = (float*)d_out;
  float* out_c = out_h + 4194304;

  char* ws = (char*)d_ws;
  u16*   HSb  = (u16*)(ws + 0);          // 8 MB   (reused as O after gemm1)
  u16*   O    = (u16*)(ws + 0);
  u16*   WvT  = (u16*)(ws + 8388608);    // 2 MB
  u16*   WoT  = (u16*)(ws + 10485760);   // 2 MB
  u16*   Zw   = (u16*)(ws + 12582912);   // 2 MB
  float* zsqw = (float*)(ws + 14680064); // 0.25 MB
  u16*   Vw   = (u16*)(ws + 14942208);   // 8 MB
  u16*   VFw  = (u16*)(ws + 23330816);   // 8 MB  -> total 31.7 MB

  k_cvt<<<4096, 256, 0, stream>>>(hs, HSb, 4194304);
  k_wT<<<256, 256, 0, stream>>>(Wv, WvT);
  k_wT<<<256, 256, 0, stream>>>(Wo, WoT);
  k_z<<<256, 256, 0, stream>>>(coords, Wc, bc, Zw, zsqw);
  k_gemm<1><<<512, 256, 0, stream>>>(HSb, WvT, bv, Vw, 4096, 1024, 1024);
  k_vF<<<1024, 256, 0, stream>>>(Vw, VFw);
  k_attn<<<1024, 256, 0, stream>>>(Zw, zsqw, VFw, gamma, O);
  k_gemm<0><<<512, 256, 0, stream>>>(O, WoT, bo, out_h, 4096, 1024, 1024);
  k_coords<<<1024, 256, 0, stream>>>(coords, Wn, bn, out_c);
}